// Round 2
// 283.143 us; speedup vs baseline: 1.0899x; 1.0899x over previous
//
#include <hip/hip_runtime.h>

// FractalEmbedding: out[b,l,d] = scale * sum_f feats(token)[f] * W[d,f]
// feats = 8-step Julia iteration on c_table[token], interleaved (zr,zi).
//
// B=8, L=8192 -> 65536 tokens; D=1024; 16 features. Output = 268 MB f32.
// Write-BW bound in principle (41 us at 6.5 TB/s) but the v0 kernel ran
// ~143 us: per-token loop was serialized on tok->ctab dependent loads and a
// single Julia dependency chain. This version:
//   * processes 4 tokens per iteration (int4 token load, 4 ctab gathers in
//     flight, 4 interleaved Julia chains -> 4-way ILP, 16 KB stores/iter)
//   * prefetches the next token group one iteration ahead
//   * fuses the feature->dot accumulation into the Julia loop (no f[16] array;
//     same ascending-k FMA order as the reference loop)
//   * nontemporal stores via clang ext_vector float4 (HIP float4 is a class
//     type the builtin rejects)
//   * scale folded into the register-resident W (scale==1.0 -> bit-identical)

#define STEPS 8
#define NFEAT (2 * STEPS)
#define EMBED 1024
#define NTOK (8 * 8192)
#define TB 4                    // tokens per iteration
#define NGRP (NTOK / TB)        // 16384 groups
#define BLOCK 256
#define GRID 2048               // 8 iterations per block, exact

typedef float v4f __attribute__((ext_vector_type(4)));

__global__ __launch_bounds__(BLOCK, 4) void FractalEmbedding_30365418782757_kernel(
    const int* __restrict__ tok,
    const float* __restrict__ ctab,   // (V, 2)
    const float* __restrict__ W,      // (1024, 16) row-major
    const float* __restrict__ scale_p,
    float* __restrict__ out)          // (NTOK, 1024)
{
    const int t = threadIdx.x;  // thread t -> output dims 4t .. 4t+3
    const float s = *scale_p;

    // This thread's 4 W rows in registers, scale pre-folded (64 VGPRs).
    float w[4][NFEAT];
#pragma unroll
    for (int r = 0; r < 4; ++r) {
        const float4* wrow = reinterpret_cast<const float4*>(W + (size_t)(4 * t + r) * NFEAT);
#pragma unroll
        for (int q = 0; q < 4; ++q) {
            float4 v = wrow[q];
            w[r][4 * q + 0] = v.x * s;
            w[r][4 * q + 1] = v.y * s;
            w[r][4 * q + 2] = v.z * s;
            w[r][4 * q + 3] = v.w * s;
        }
    }

    const int4*   tok4 = reinterpret_cast<const int4*>(tok);
    const float2* c2   = reinterpret_cast<const float2*>(ctab);

    int  g   = blockIdx.x;
    int4 ids = tok4[g];                       // preload first group
    while (g < NGRP) {
        const int gnext = g + gridDim.x;

        // 4 independent c gathers issue immediately (ids already resident).
        float2 ca = c2[ids.x];
        float2 cb = c2[ids.y];
        float2 cc = c2[ids.z];
        float2 cd = c2[ids.w];

        // Prefetch next group's token ids (clamped: harmless redundant load on
        // the final iteration; keeps the load unconditional and early).
        const int gpf = (gnext < NGRP) ? gnext : g;
        int4 nids = tok4[gpf];

        // 4 interleaved Julia chains, dot-accumulation fused per step.
        float zr0 = 0.f, zi0 = 0.f, zr1 = 0.f, zi1 = 0.f;
        float zr2 = 0.f, zi2 = 0.f, zr3 = 0.f, zi3 = 0.f;
        float acc[TB][4];
#pragma unroll
        for (int j = 0; j < TB; ++j)
#pragma unroll
            for (int r = 0; r < 4; ++r) acc[j][r] = 0.f;

#pragma unroll
        for (int st = 0; st < STEPS; ++st) {
            float a0 = zr0 * zr0 - zi0 * zi0 + ca.x;  float b0 = 2.0f * zr0 * zi0 + ca.y;
            float a1 = zr1 * zr1 - zi1 * zi1 + cb.x;  float b1 = 2.0f * zr1 * zi1 + cb.y;
            float a2 = zr2 * zr2 - zi2 * zi2 + cc.x;  float b2 = 2.0f * zr2 * zi2 + cc.y;
            float a3 = zr3 * zr3 - zi3 * zi3 + cd.x;  float b3 = 2.0f * zr3 * zi3 + cd.y;
            zr0 = a0; zi0 = b0; zr1 = a1; zi1 = b1;
            zr2 = a2; zi2 = b2; zr3 = a3; zi3 = b3;
#pragma unroll
            for (int r = 0; r < 4; ++r) {
                // same ascending-feature FMA order as the original dot loop
                acc[0][r] += zr0 * w[r][2 * st]; acc[0][r] += zi0 * w[r][2 * st + 1];
                acc[1][r] += zr1 * w[r][2 * st]; acc[1][r] += zi1 * w[r][2 * st + 1];
                acc[2][r] += zr2 * w[r][2 * st]; acc[2][r] += zi2 * w[r][2 * st + 1];
                acc[3][r] += zr3 * w[r][2 * st]; acc[3][r] += zi3 * w[r][2 * st + 1];
            }
        }

        // Store 4 token rows (16 KB per block-iteration), streaming.
        v4f* obase = reinterpret_cast<v4f*>(out + (size_t)(TB * g) * EMBED) + t;
#pragma unroll
        for (int j = 0; j < TB; ++j) {
            v4f o;
            o.x = acc[j][0]; o.y = acc[j][1]; o.z = acc[j][2]; o.w = acc[j][3];
            __builtin_nontemporal_store(o, obase + j * (EMBED / 4));
        }

        ids = nids;
        g   = gnext;
    }
}

extern "C" void kernel_launch(void* const* d_in, const int* in_sizes, int n_in,
                              void* d_out, int out_size, void* d_ws, size_t ws_size,
                              hipStream_t stream) {
    const int*   tok   = (const int*)d_in[0];
    const float* ctab  = (const float*)d_in[1];
    const float* W     = (const float*)d_in[2];
    const float* scale = (const float*)d_in[3];
    float*       out   = (float*)d_out;

    FractalEmbedding_30365418782757_kernel<<<GRID, BLOCK, 0, stream>>>(tok, ctab, W, scale, out);
}

// Round 3
// 276.709 us; speedup vs baseline: 1.1152x; 1.0233x over previous
//
#include <hip/hip_runtime.h>

// FractalEmbedding: out[b,l,d] = scale * sum_f feats(token)[f] * W[d,f]
// feats = 8-step Julia iteration on c_table[token], interleaved (zr,zi).
//
// B=8, L=8192 -> 65536 tokens; D=1024; 16 features. Output = 268 MB f32.
// Roofline: store-BW floor ~42 us (268 MB @ 6.4 TB/s), VALU issue floor
// ~21 us. v2 ran ~116 us: the ctab gathers (dependent loads, ~200-900 cyc)
// still headed every iteration's critical path — only the token ids were
// prefetched. This version pipelines the LOAD SIDE one stage deeper:
//   iter i: issue ctab gathers for i+1 (ids already in regs),
//           issue token-id load for i+2,
//           compute + store iteration i entirely from registers.
// Gather latency now hides under the ~256 FMAs of the current iteration.
//   * 4 tokens/iter, 4 interleaved Julia chains (ILP), fused dot
//   * counted loop (exactly 8 iters/block), nontemporal float4 stores
//   * scale folded into register-resident W (scale==1.0 -> bit-identical)
// VGPR budget ~115: stays under the __launch_bounds__(256,4) 128-reg cap,
// occupancy 4 waves/SIMD.

#define STEPS 8
#define NFEAT (2 * STEPS)
#define EMBED 1024
#define NTOK (8 * 8192)
#define TB 4                    // tokens per iteration
#define NGRP (NTOK / TB)        // 16384 groups
#define BLOCK 256
#define GRID 2048               // NGRP/GRID = 8 iterations per block, exact
#define ITERS (NGRP / GRID)

typedef float v4f __attribute__((ext_vector_type(4)));

__global__ __launch_bounds__(BLOCK, 4) void FractalEmbedding_30365418782757_kernel(
    const int* __restrict__ tok,
    const float* __restrict__ ctab,   // (V, 2)
    const float* __restrict__ W,      // (1024, 16) row-major
    const float* __restrict__ scale_p,
    float* __restrict__ out)          // (NTOK, 1024)
{
    const int t = threadIdx.x;  // thread t -> output dims 4t .. 4t+3
    const float s = *scale_p;

    // This thread's 4 W rows in registers, scale pre-folded (64 VGPRs).
    float w[4][NFEAT];
#pragma unroll
    for (int r = 0; r < 4; ++r) {
        const float4* wrow = reinterpret_cast<const float4*>(W + (size_t)(4 * t + r) * NFEAT);
#pragma unroll
        for (int q = 0; q < 4; ++q) {
            float4 v = wrow[q];
            w[r][4 * q + 0] = v.x * s;
            w[r][4 * q + 1] = v.y * s;
            w[r][4 * q + 2] = v.z * s;
            w[r][4 * q + 3] = v.w * s;
        }
    }

    const int4*   tok4 = reinterpret_cast<const int4*>(tok);
    const float2* c2   = reinterpret_cast<const float2*>(ctab);
    const int     b    = blockIdx.x;

    // ---- pipeline prologue: c for iter 0, ids for iter 1 ----
    int4 ids0 = tok4[b];
    float2 ca = c2[ids0.x];
    float2 cb = c2[ids0.y];
    float2 cc = c2[ids0.z];
    float2 cd = c2[ids0.w];
    int gi1 = b + GRID;
    int4 ids = tok4[(gi1 < NGRP) ? gi1 : (NGRP - 1)];   // ids for iter i+1

    for (int i = 0; i < ITERS; ++i) {
        const int g = b + i * GRID;

        // Issue next iteration's gathers NOW (ids already resident) ...
        float2 n0 = c2[ids.x];
        float2 n1 = c2[ids.y];
        float2 n2 = c2[ids.z];
        float2 n3 = c2[ids.w];
        // ... and the ids for iteration i+2 (clamped; redundant at the tail).
        int gi2 = g + 2 * GRID;
        int4 nids = tok4[(gi2 < NGRP) ? gi2 : (NGRP - 1)];

        // ---- compute iteration i from registers ----
        float zr0 = 0.f, zi0 = 0.f, zr1 = 0.f, zi1 = 0.f;
        float zr2 = 0.f, zi2 = 0.f, zr3 = 0.f, zi3 = 0.f;
        float acc[TB][4];
#pragma unroll
        for (int j = 0; j < TB; ++j)
#pragma unroll
            for (int r = 0; r < 4; ++r) acc[j][r] = 0.f;

#pragma unroll
        for (int st = 0; st < STEPS; ++st) {
            float a0 = zr0 * zr0 - zi0 * zi0 + ca.x;  float b0 = 2.0f * zr0 * zi0 + ca.y;
            float a1 = zr1 * zr1 - zi1 * zi1 + cb.x;  float b1 = 2.0f * zr1 * zi1 + cb.y;
            float a2 = zr2 * zr2 - zi2 * zi2 + cc.x;  float b2 = 2.0f * zr2 * zi2 + cc.y;
            float a3 = zr3 * zr3 - zi3 * zi3 + cd.x;  float b3 = 2.0f * zr3 * zi3 + cd.y;
            zr0 = a0; zi0 = b0; zr1 = a1; zi1 = b1;
            zr2 = a2; zi2 = b2; zr3 = a3; zi3 = b3;
#pragma unroll
            for (int r = 0; r < 4; ++r) {
                // same ascending-feature FMA order as the reference dot loop
                acc[0][r] += zr0 * w[r][2 * st]; acc[0][r] += zi0 * w[r][2 * st + 1];
                acc[1][r] += zr1 * w[r][2 * st]; acc[1][r] += zi1 * w[r][2 * st + 1];
                acc[2][r] += zr2 * w[r][2 * st]; acc[2][r] += zi2 * w[r][2 * st + 1];
                acc[3][r] += zr3 * w[r][2 * st]; acc[3][r] += zi3 * w[r][2 * st + 1];
            }
        }

        // Store 4 token rows (16 KB per block-iteration), streaming.
        v4f* obase = reinterpret_cast<v4f*>(out + (size_t)(TB * g) * EMBED) + t;
#pragma unroll
        for (int j = 0; j < TB; ++j) {
            v4f o;
            o.x = acc[j][0]; o.y = acc[j][1]; o.z = acc[j][2]; o.w = acc[j][3];
            __builtin_nontemporal_store(o, obase + j * (EMBED / 4));
        }

        // ---- rotate pipeline registers ----
        ca = n0; cb = n1; cc = n2; cd = n3;
        ids = nids;
    }
}

extern "C" void kernel_launch(void* const* d_in, const int* in_sizes, int n_in,
                              void* d_out, int out_size, void* d_ws, size_t ws_size,
                              hipStream_t stream) {
    const int*   tok   = (const int*)d_in[0];
    const float* ctab  = (const float*)d_in[1];
    const float* W     = (const float*)d_in[2];
    const float* scale = (const float*)d_in[3];
    float*       out   = (float*)d_out;

    FractalEmbedding_30365418782757_kernel<<<GRID, BLOCK, 0, stream>>>(tok, ctab, W, scale, out);
}

// Round 4
// 266.526 us; speedup vs baseline: 1.1578x; 1.0382x over previous
//
#include <hip/hip_runtime.h>

// FractalEmbedding: out[b,l,d] = scale * sum_f feats(token)[f] * W[d,f]
// feats = 8-step Julia iteration on c_table[token], interleaved (zr,zi).
//
// B=8, L=8192 -> 65536 tokens; D=1024; 16 features. Output = 268 MB f32.
// Floors: store-BW ~42 us (fill kernel proves 6.4 TB/s on this machine),
// VALU issue ~20-24 us. v3 ran ~110 us despite deep load pipelining ->
// the stall is NOT gather latency. Two suspects addressed here:
//   1) VGPR spill: v3 needed ~125-135 regs under a 128-reg launch_bounds cap
//      -> possible scratch spill of the W registers. This version maps
//      512 threads/block x 2 W-rows/thread: w shrinks 64->32 VGPRs,
//      total ~90 regs, no cap, occupancy ~5 waves/SIMD.
//   2) Nontemporal stores: nt bypasses L2, so register-recycle vmcnt waits
//      complete at HBM (~1000 cyc). Plain stores complete into L2 (the
//      6.4 TB/s fill uses plain stores). NT dropped.
// Also: dot + Julia written in packed float2 so the compiler can emit
// v_pk_fma_f32 (CDNA4 packed f32), halving VALU issue. Element-wise op
// order unchanged -> bit-identical to the passing v3.

#define STEPS 8
#define NFEAT (2 * STEPS)
#define EMBED 1024
#define NTOK (8 * 8192)
#define TB 4                    // tokens per iteration
#define NGRP (NTOK / TB)        // 16384 groups
#define BLOCK 512               // thread t -> output dims 2t, 2t+1
#define GRID 2048               // NGRP/GRID = 8 iterations per block, exact
#define ITERS (NGRP / GRID)

typedef float v2f __attribute__((ext_vector_type(2)));

__global__ __launch_bounds__(BLOCK) void FractalEmbedding_30365418782757_kernel(
    const int* __restrict__ tok,
    const float* __restrict__ ctab,   // (V, 2)
    const float* __restrict__ W,      // (1024, 16) row-major
    const float* __restrict__ scale_p,
    float* __restrict__ out)          // (NTOK, 1024)
{
    const int t = threadIdx.x;        // dims 2t, 2t+1
    const float s = *scale_p;

    // Two W rows per thread, pair-interleaved for packed FMA; scale folded.
    v2f w2[NFEAT];                    // w2[k] = { W[2t][k], W[2t+1][k] } * s
    {
        const float4* r0 = reinterpret_cast<const float4*>(W + (size_t)(2 * t)     * NFEAT);
        const float4* r1 = reinterpret_cast<const float4*>(W + (size_t)(2 * t + 1) * NFEAT);
#pragma unroll
        for (int q = 0; q < 4; ++q) {
            float4 a = r0[q];
            float4 b = r1[q];
            w2[4 * q + 0] = (v2f){a.x * s, b.x * s};
            w2[4 * q + 1] = (v2f){a.y * s, b.y * s};
            w2[4 * q + 2] = (v2f){a.z * s, b.z * s};
            w2[4 * q + 3] = (v2f){a.w * s, b.w * s};
        }
    }

    const int4*   tok4 = reinterpret_cast<const int4*>(tok);
    const float2* c2   = reinterpret_cast<const float2*>(ctab);
    const int     b    = blockIdx.x;

    // ---- pipeline prologue: c for iter 0, ids for iter 1 ----
    int4 ids0 = tok4[b];
    float2 ca = c2[ids0.x];
    float2 cb = c2[ids0.y];
    float2 cc = c2[ids0.z];
    float2 cd = c2[ids0.w];
    int gi1 = b + GRID;
    int4 ids = tok4[(gi1 < NGRP) ? gi1 : (NGRP - 1)];

    for (int i = 0; i < ITERS; ++i) {
        const int g = b + i * GRID;

        // Issue next iteration's gathers now (ids already resident) ...
        float2 n0 = c2[ids.x];
        float2 n1 = c2[ids.y];
        float2 n2 = c2[ids.z];
        float2 n3 = c2[ids.w];
        // ... and ids for iteration i+2 (clamped; redundant at the tail).
        int gi2 = g + 2 * GRID;
        int4 nids = tok4[(gi2 < NGRP) ? gi2 : (NGRP - 1)];

        // ---- compute iteration i, packed across token pairs ----
        // chains A = tokens {0,1}, B = tokens {2,3}
        v2f cxA = (v2f){ca.x, cb.x}, cyA = (v2f){ca.y, cb.y};
        v2f cxB = (v2f){cc.x, cd.x}, cyB = (v2f){cc.y, cd.y};
        v2f zrA = (v2f){0.f, 0.f}, ziA = zrA, zrB = zrA, ziB = zrA;
        v2f acc0 = zrA, acc1 = zrA, acc2 = zrA, acc3 = zrA;  // per-token {row2t,row2t+1}

#pragma unroll
        for (int st = 0; st < STEPS; ++st) {
            v2f aA = zrA * zrA - ziA * ziA + cxA;
            v2f bA = 2.0f * zrA * ziA + cyA;
            v2f aB = zrB * zrB - ziB * ziB + cxB;
            v2f bB = 2.0f * zrB * ziB + cyB;
            zrA = aA; ziA = bA; zrB = aB; ziB = bB;
            // same ascending-feature accumulation order as the reference
            acc0 += zrA.x * w2[2 * st]; acc0 += ziA.x * w2[2 * st + 1];
            acc1 += zrA.y * w2[2 * st]; acc1 += ziA.y * w2[2 * st + 1];
            acc2 += zrB.x * w2[2 * st]; acc2 += ziB.x * w2[2 * st + 1];
            acc3 += zrB.y * w2[2 * st]; acc3 += ziB.y * w2[2 * st + 1];
        }

        // Store 4 token rows (16 KB per block-iteration), plain dwordx2.
        v2f* obase = reinterpret_cast<v2f*>(out + (size_t)(TB * g) * EMBED) + t;
        obase[0 * (EMBED / 2)] = acc0;
        obase[1 * (EMBED / 2)] = acc1;
        obase[2 * (EMBED / 2)] = acc2;
        obase[3 * (EMBED / 2)] = acc3;

        // ---- rotate pipeline registers ----
        ca = n0; cb = n1; cc = n2; cd = n3;
        ids = nids;
    }
}

extern "C" void kernel_launch(void* const* d_in, const int* in_sizes, int n_in,
                              void* d_out, int out_size, void* d_ws, size_t ws_size,
                              hipStream_t stream) {
    const int*   tok   = (const int*)d_in[0];
    const float* ctab  = (const float*)d_in[1];
    const float* W     = (const float*)d_in[2];
    const float* scale = (const float*)d_in[3];
    float*       out   = (float*)d_out;

    FractalEmbedding_30365418782757_kernel<<<GRID, BLOCK, 0, stream>>>(tok, ctab, W, scale, out);
}